// Round 12
// baseline (755.725 us; speedup 1.0000x reference)
//
#include <hip/hip_runtime.h>

#define B_   8
#define L_   512
#define H_   768
#define NH_  12
#define DFF_ 3072
#define NL_  4
#define HD_  64
#define M_   4096

typedef __bf16 bf16x8 __attribute__((ext_vector_type(8)));
typedef float f32x4 __attribute__((ext_vector_type(4)));
typedef unsigned short u16x8 __attribute__((ext_vector_type(8)));

__device__ inline float bf2f(unsigned short u){
  union { unsigned int i; float f; } v; v.i = ((unsigned int)u) << 16; return v.f;
}
__device__ inline unsigned short f2bf(float f){
  union { float f; unsigned int i; } v; v.f = f;
  unsigned int x = v.i;
  return (unsigned short)((x + 0x7fffu + ((x >> 16) & 1u)) >> 16);
}

// ---------------- weight prep: transpose fp32 [R][C] -> bf16 [C][R] ----------------
__global__ __launch_bounds__(256) void k_prep_weights(const float* __restrict__ Wq, const float* __restrict__ Wk,
                               const float* __restrict__ Wv, const float* __restrict__ Wo,
                               const float* __restrict__ W1, const float* __restrict__ W2,
                               unsigned short* __restrict__ wTall){
  __shared__ float tile[64][65];
  int id = blockIdx.x;
  int layer = id / 1728;
  int r = id % 1728;
  unsigned short* wt = wTall + (size_t)layer * 7077888;
  const float* src; unsigned short* dst; int R, C, tr, tilesC;
  if (r < 576){
    int mat = r / 144; tr = r % 144; R = 768; C = 768; tilesC = 12;
    const float* s;
    if (mat == 0) s = Wq; else if (mat == 1) s = Wk; else if (mat == 2) s = Wv; else s = Wo;
    src = s + (size_t)layer * 589824;
    dst = wt + (size_t)mat * 589824;
  } else if (r < 1152){
    tr = r - 576; R = 768; C = 3072; tilesC = 48;
    src = W1 + (size_t)layer * 2359296; dst = wt + 2359296;
  } else {
    tr = r - 1152; R = 3072; C = 768; tilesC = 12;
    src = W2 + (size_t)layer * 2359296; dst = wt + 4718592;
  }
  int r0 = (tr / tilesC) << 6, c0 = (tr % tilesC) << 6;
  int tid = threadIdx.x;
  int tx = tid & 15, ty = tid >> 4;
  #pragma unroll
  for (int i = 0; i < 4; i++){
    int row = ty + i * 16;
    float4 v = *(const float4*)(src + (size_t)(r0 + row) * C + c0 + tx * 4);
    tile[row][tx * 4] = v.x; tile[row][tx * 4 + 1] = v.y;
    tile[row][tx * 4 + 2] = v.z; tile[row][tx * 4 + 3] = v.w;
  }
  __syncthreads();
  int rr = (tid & 7) * 8;
  #pragma unroll
  for (int i = 0; i < 2; i++){
    int col = (tid >> 3) + i * 32;
    u16x8 o;
    #pragma unroll
    for (int j = 0; j < 8; j++) o[j] = f2bf(tile[rr + j][col]);
    *(u16x8*)(dst + (size_t)(c0 + col) * R + r0 + rr) = o;
  }
}

__global__ void k_prep_bias(const float* __restrict__ bq, const float* __restrict__ bk,
                            const float* __restrict__ bv, float* __restrict__ out){
  int i = blockIdx.x * 256 + threadIdx.x;
  int layer = i / 2304, c = i % 2304;
  float v;
  if (c < 768) v = bq[layer * 768 + c];
  else if (c < 1536) v = bk[layer * 768 + c - 768];
  else v = bv[layer * 768 + c - 1536];
  out[i] = v;
}

// ---------------- embedding + LN ----------------
__global__ __launch_bounds__(256) void k_embed_ln(const int* __restrict__ ids, const int* __restrict__ tts,
                           const float* __restrict__ we, const float* __restrict__ pe,
                           const float* __restrict__ te, const float* __restrict__ g,
                           const float* __restrict__ b,
                           unsigned short* __restrict__ xb){
  int row = blockIdx.x;
  int l = row & 511;
  int id = ids[row], tt = tts[row];
  int t = threadIdx.x;
  float v[3]; float s = 0.f, s2 = 0.f;
  #pragma unroll
  for (int i = 0; i < 3; i++){
    int c = t + i * 256;
    float val = we[(size_t)id * 768 + c] + pe[(size_t)l * 768 + c] + te[(size_t)tt * 768 + c];
    v[i] = val; s += val; s2 += val * val;
  }
  #pragma unroll
  for (int o = 32; o > 0; o >>= 1){ s += __shfl_down(s, o); s2 += __shfl_down(s2, o); }
  __shared__ float red[2][4];
  int wv = t >> 6;
  if ((t & 63) == 0){ red[0][wv] = s; red[1][wv] = s2; }
  __syncthreads();
  s = red[0][0] + red[0][1] + red[0][2] + red[0][3];
  s2 = red[1][0] + red[1][1] + red[1][2] + red[1][3];
  float mean = s * (1.f / 768.f);
  float var = s2 * (1.f / 768.f) - mean * mean;
  float rstd = rsqrtf(var + 1e-12f);
  #pragma unroll
  for (int i = 0; i < 3; i++){
    int c = t + i * 256;
    float nv = (v[i] - mean) * rstd * g[c] + b[c];
    xb[(size_t)row * 768 + c] = f2bf(nv);
  }
}

// ---------------- residual add + N2 bf16 partials + LN (vectorized) ----------------
template<int N2>
__global__ __launch_bounds__(128) void k_add_ln(unsigned short* __restrict__ xb,
                         const unsigned short* __restrict__ y,
                         const unsigned short* __restrict__ y2,
                         const float* __restrict__ g, const float* __restrict__ b){
  int row = blockIdx.x;
  int t = threadIdx.x;
  float v[8];
  float s = 0.f, s2 = 0.f;
  size_t base = (size_t)row * 768 + t * 8;
  if (t < 96){
    u16x8 a = *(const u16x8*)(xb + base);
    u16x8 yy = *(const u16x8*)(y + base);
    #pragma unroll
    for (int j = 0; j < 8; j++) v[j] = bf2f(a[j]) + bf2f(yy[j]);
    #pragma unroll
    for (int q = 0; q < N2; q++){
      u16x8 p = *(const u16x8*)(y2 + (size_t)q * 4096 * 768 + base);
      #pragma unroll
      for (int j = 0; j < 8; j++) v[j] += bf2f(p[j]);
    }
    #pragma unroll
    for (int j = 0; j < 8; j++){ s += v[j]; s2 += v[j] * v[j]; }
  }
  #pragma unroll
  for (int o = 32; o > 0; o >>= 1){ s += __shfl_down(s, o); s2 += __shfl_down(s2, o); }
  __shared__ float red[2][2];
  int wv = t >> 6;
  if ((t & 63) == 0){ red[0][wv] = s; red[1][wv] = s2; }
  __syncthreads();
  s = red[0][0] + red[0][1];
  s2 = red[1][0] + red[1][1];
  float mean = s * (1.f / 768.f);
  float var = s2 * (1.f / 768.f) - mean * mean;
  float rstd = rsqrtf(var + 1e-12f);
  if (t < 96){
    f32x4 g0 = *(const f32x4*)(g + t * 8);
    f32x4 g1 = *(const f32x4*)(g + t * 8 + 4);
    f32x4 b0 = *(const f32x4*)(b + t * 8);
    f32x4 b1 = *(const f32x4*)(b + t * 8 + 4);
    u16x8 o8;
    #pragma unroll
    for (int j = 0; j < 4; j++) o8[j] = f2bf((v[j] - mean) * rstd * g0[j] + b0[j]);
    #pragma unroll
    for (int j = 0; j < 4; j++) o8[4 + j] = f2bf((v[4 + j] - mean) * rstd * g1[j] + b1[j]);
    *(u16x8*)(xb + base) = o8;
  }
}

// ---------------- 128^2 2-phase GEMM (proven; Wo/FF2 split-K) ----------------
template<int ACT>
__global__ __launch_bounds__(256, 4) void k_gemm(const unsigned short* __restrict__ A,
                                              const unsigned short* __restrict__ BT,
                                              const float* __restrict__ bias,
                                              unsigned short* __restrict__ Cout,
                                              unsigned short* __restrict__ Cout2,
                                              int M, int N, int K, int Ksub){
  __shared__ __attribute__((aligned(16))) unsigned short smem[16384];
  unsigned short* As = smem;
  unsigned short* Bs = smem + 8192;
  int tid = threadIdx.x;
  int lane = tid & 63, wave = tid >> 6;
  int lr = lane & 15, lg = lane >> 4;

  int gx = gridDim.x;
  int nwg = gx * gridDim.y;
  int flat = blockIdx.y * gx + blockIdx.x;
  int cpx = nwg >> 3;
  int swz = (flat & 7) * cpx + (flat >> 3);
  int bx = swz % gx, by = swz / gx;

  int bm0 = by * 128, bn0 = bx * 128;
  int wr = wave >> 1, wc = wave & 1;
  int kz = blockIdx.z * Ksub;

  f32x4 acc[4][4];
  #pragma unroll
  for (int m = 0; m < 4; m++)
    #pragma unroll
    for (int n = 0; n < 4; n++)
      acc[m][n] = (f32x4){0.f, 0.f, 0.f, 0.f};

  int scol = (((lane & 7) ^ (lane >> 3)) << 3);
  const unsigned short* gaBase = A + (size_t)(bm0 + (lane >> 3)) * K + kz + scol;
  const unsigned short* gbBase = BT + (size_t)(bn0 + (lane >> 3)) * K + kz + scol;

  int nk = Ksub >> 6;
  for (int t = 0; t < nk; t++){
    if (t) __syncthreads();
    const unsigned short* gA = gaBase + (t << 6);
    const unsigned short* gB = gbBase + (t << 6);
    #pragma unroll
    for (int i = 0; i < 4; i++){
      size_t ro = (size_t)((wave * 4 + i) * 8) * K;
      __builtin_amdgcn_global_load_lds(
        (const __attribute__((address_space(1))) void*)(gA + ro),
        (__attribute__((address_space(3))) void*)(As + (wave * 4 + i) * 512), 16, 0, 0);
      __builtin_amdgcn_global_load_lds(
        (const __attribute__((address_space(1))) void*)(gB + ro),
        (__attribute__((address_space(3))) void*)(Bs + (wave * 4 + i) * 512), 16, 0, 0);
    }
    __syncthreads();
    #pragma unroll
    for (int kk = 0; kk < 2; kk++){
      bf16x8 av[4], bv[4];
      #pragma unroll
      for (int m = 0; m < 4; m++)
        av[m] = *(const bf16x8*)(As + (wr * 64 + m * 16 + lr) * 64 + (((4 * kk + lg) ^ (lr & 7)) << 3));
      #pragma unroll
      for (int n = 0; n < 4; n++)
        bv[n] = *(const bf16x8*)(Bs + (wc * 64 + n * 16 + lr) * 64 + (((4 * kk + lg) ^ (lr & 7)) << 3));
      #pragma unroll
      for (int m = 0; m < 4; m++)
        #pragma unroll
        for (int n = 0; n < 4; n++)
          acc[m][n] = __builtin_amdgcn_mfma_f32_16x16x32_bf16(av[m], bv[n], acc[m][n], 0, 0, 0);
    }
  }
  __syncthreads();

  int r0 = wr * 64 + 4 * lg;
  int c0 = wc * 64 + lr;
  unsigned short* cs = smem;
  bool z0 = (blockIdx.z == 0);
  #pragma unroll
  for (int n = 0; n < 4; n++){
    int c = c0 + 16 * n;
    float bsv = z0 ? bias[bn0 + c] : 0.f;
    #pragma unroll
    for (int m = 0; m < 4; m++)
      #pragma unroll
      for (int j = 0; j < 4; j++){
        float v = acc[m][n][j] + bsv;
        if (ACT == 1) v = 0.5f * v * (1.f + erff(v * 0.70710678118f));
        cs[(r0 + m * 16 + j) * 128 + c] = f2bf(v);
      }
  }
  __syncthreads();
  unsigned short* Cb = z0 ? Cout : (Cout2 + (size_t)(blockIdx.z - 1) * M * N);
  #pragma unroll
  for (int p = 0; p < 8; p++){
    int idx = p * 2048 + tid * 8;
    int row = idx >> 7, col = idx & 127;
    u16x8 v = *(const u16x8*)(cs + idx);
    *(u16x8*)(Cb + (size_t)(bm0 + row) * N + bn0 + col) = v;
  }
}

// ---------------- 256^2 8-phase counted-vmcnt GEMM (arrival-correct rebuild) ----------------
// Per-phase READ-SETS derived from the wave mapping (union over all 8 waves):
//   P0=(MQ0,NQ0): A quarters {0,2} (rows 0-63,128-191) + B even 32-blocks {0,2,4,6}
//   P1=(MQ0,NQ1): A {0,2} + B odd blocks {1,3,5,7}
//   P2=(MQ1,NQ0): A quarters {1,3} + B even
//   P3=(MQ1,NQ1): A {1,3} + B odd
// Staging units (1 gload_lds instr per wave each = 1 vmcnt event/wave):
//   A(q): 64 rows q*64.. ; B(p,h): waves0-3 -> block h*4+p, waves4-7 -> block h*4+p+2.
// Tile x+1's 8 units ALL issued during tile x (buf^1 idle for the whole of tile x:
// last read ended at x-1.P3 barrier, next read at x+1.P0). Issue order & deadlines:
//   x.P0: A(0),A(2)   -> needed x+1.P0   (4 phases slack)
//   x.P1: B(0,0),B(0,1) -> x+1.P0        (3)
//   x.P2: B(1,0),B(1,1) -> x+1.P1        (3)
//   x.P3: A(1),A(3)   -> x+1.P2          (3)
// Waits (2 events/phase, FIFO per m135): end P0: vmcnt(4); end P1: vmcnt(4);
// end P2: vmcnt(6); end P3: vmcnt(4). Never zero in the loop. Last tile peeled
// with vmcnt(2)/vmcnt(0). nk = K/64 >= 2 required.
#define WAITV(n) do { asm volatile("s_waitcnt vmcnt(" #n ")" ::: "memory"); \
  __builtin_amdgcn_sched_barrier(0); __builtin_amdgcn_s_barrier(); \
  __builtin_amdgcn_sched_barrier(0); } while(0)

template<int ACT>
__global__ __launch_bounds__(512, 2) void k_gemm8(const unsigned short* __restrict__ A,
                                                  const unsigned short* __restrict__ BT,
                                                  const float* __restrict__ bias,
                                                  unsigned short* __restrict__ Cout,
                                                  int M, int N, int K){
  __shared__ __attribute__((aligned(16))) unsigned short smem[65536]; // 128 KB
  int tid = threadIdx.x;
  int lane = tid & 63, wave = tid >> 6;
  int lr = lane & 15, lg = lane >> 4;
  int wr = wave >> 2, wc = wave & 3;

  int gx = gridDim.x;
  int nwg = gx * gridDim.y;
  int flat = blockIdx.y * gx + blockIdx.x;
  int cpx = nwg >> 3;
  int swz = (flat & 7) * cpx + (flat >> 3);
  int bx = swz % gx, by = swz / gx;
  int bm0 = by * 256, bn0 = bx * 256;

  f32x4 acc[8][4];
  #pragma unroll
  for (int m = 0; m < 8; m++)
    #pragma unroll
    for (int n = 0; n < 4; n++)
      acc[m][n] = (f32x4){0.f, 0.f, 0.f, 0.f};

  int scol = (((lane & 7) ^ (lane >> 3)) << 3);
  const unsigned short* gAl = A + (size_t)(bm0 + (lane >> 3)) * K + scol;
  const unsigned short* gBl = BT + (size_t)(bn0 + (lane >> 3)) * K + scol;

  auto STG_A = [&](int buf, int q, int tile){
    int R0 = q * 64 + wave * 8;
    const unsigned short* g = gAl + (size_t)R0 * K + tile * 64;
    unsigned short* d = smem + buf * 32768 + R0 * 64;
    __builtin_amdgcn_global_load_lds(
      (const __attribute__((address_space(1))) void*)g,
      (__attribute__((address_space(3))) void*)d, 16, 0, 0);
  };
  auto STG_B = [&](int buf, int p, int h, int tile){
    int blk = h * 4 + p + ((wave >> 2) << 1);       // waves 4-7 take block +2
    int R0 = blk * 32 + (wave & 3) * 8;
    const unsigned short* g = gBl + (size_t)R0 * K + tile * 64;
    unsigned short* d = smem + buf * 32768 + 16384 + R0 * 64;
    __builtin_amdgcn_global_load_lds(
      (const __attribute__((address_space(1))) void*)g,
      (__attribute__((address_space(3))) void*)d, 16, 0, 0);
  };

#define QUAD(BUF, MQ, NQ) { \
  const unsigned short* as_ = smem + (BUF) * 32768; \
  const unsigned short* bs_ = as_ + 16384; \
  bf16x8 av[4][2], bv[2][2]; \
  _Pragma("unroll") for (int a = 0; a < 4; a++){ \
    int row_ = wr * 128 + ((MQ) * 4 + a) * 16 + lr; \
    _Pragma("unroll") for (int ks = 0; ks < 2; ks++) \
      av[a][ks] = *(const bf16x8*)(as_ + row_ * 64 + (((ks * 4 + lg) ^ (lr & 7)) << 3)); \
  } \
  _Pragma("unroll") for (int b2_ = 0; b2_ < 2; b2_++){ \
    int row_ = wc * 64 + ((NQ) * 2 + b2_) * 16 + lr; \
    _Pragma("unroll") for (int ks = 0; ks < 2; ks++) \
      bv[b2_][ks] = *(const bf16x8*)(bs_ + row_ * 64 + (((ks * 4 + lg) ^ (lr & 7)) << 3)); \
  } \
  __builtin_amdgcn_s_setprio(1); \
  _Pragma("unroll") for (int ks = 0; ks < 2; ks++) \
    _Pragma("unroll") for (int a = 0; a < 4; a++) \
      _Pragma("unroll") for (int b2_ = 0; b2_ < 2; b2_++) \
        acc[(MQ) * 4 + a][(NQ) * 2 + b2_] = __builtin_amdgcn_mfma_f32_16x16x32_bf16( \
          av[a][ks], bv[b2_][ks], acc[(MQ) * 4 + a][(NQ) * 2 + b2_], 0, 0, 0); \
  __builtin_amdgcn_s_setprio(0); \
}

  int nk = K >> 6;   // >= 2

  // prologue: tile 0 -> buf0, issued in deadline order (events 1..8)
  STG_A(0,0,0); STG_A(0,2,0);           // ev1,2  needed 0.P0
  STG_B(0,0,0,0); STG_B(0,0,1,0);       // ev3,4  needed 0.P0
  STG_B(0,1,0,0); STG_B(0,1,1,0);       // ev5,6  needed 0.P1
  STG_A(0,1,0); STG_A(0,3,0);           // ev7,8  needed 0.P2
  WAITV(4);   // ev1-4 complete -> P0 ready

  for (int x = 0; x < nk - 1; x++){
    int buf = x & 1, sb = buf ^ 1, nt = x + 1;
    STG_A(sb,0,nt); STG_A(sb,2,nt);
    QUAD(buf,0,0)
    WAITV(4);                 // guarantees tile-x Bod (issued prev P2) complete
    STG_B(sb,0,0,nt); STG_B(sb,0,1,nt);
    QUAD(buf,0,1)
    WAITV(4);                 // guarantees tile-x Aq1,3 (issued prev P3) complete
    STG_B(sb,1,0,nt); STG_B(sb,1,1,nt);
    QUAD(buf,1,0)
    WAITV(6);                 // rhythm only; no new deadline
    STG_A(sb,1,nt); STG_A(sb,3,nt);
    QUAD(buf,1,1)
    WAITV(4);                 // guarantees tile-(x+1) Aq0,2 + Bev complete
  }

  // peeled last tile (no issues): outstanding entering = 4 (Bod@P2, Aq1,3@P3 of prev iter)
  {
    int buf = (nk - 1) & 1;
    QUAD(buf,0,0)
    WAITV(2);                 // Bod complete
    QUAD(buf,0,1)
    WAITV(0);                 // Aq1,3 complete
    QUAD(buf,1,0)
    __builtin_amdgcn_s_barrier();
    QUAD(buf,1,1)
  }
  __syncthreads();

  // epilogue: stage bf16 C tile [256][256] in LDS, linear coalesced stores
  unsigned short* cs = smem;
  int c0l = wc * 64 + lr;
  int r0l = wr * 128 + 4 * lg;
  #pragma unroll
  for (int n = 0; n < 4; n++){
    int c = c0l + 16 * n;
    float bsv = bias[bn0 + c];
    #pragma unroll
    for (int m = 0; m < 8; m++)
      #pragma unroll
      for (int j = 0; j < 4; j++){
        float v = acc[m][n][j] + bsv;
        if (ACT == 1) v = 0.5f * v * (1.f + erff(v * 0.70710678118f));
        cs[(r0l + m * 16 + j) * 256 + c] = f2bf(v);
      }
  }
  __syncthreads();
  #pragma unroll
  for (int p = 0; p < 16; p++){
    int idx = p * 4096 + tid * 8;
    int row = idx >> 8, col = idx & 255;
    u16x8 v = *(const u16x8*)(cs + idx);
    *(u16x8*)(Cout + (size_t)(bm0 + row) * N + bn0 + col) = v;
  }
#undef QUAD
}
#undef WAITV

// ---------------- MFMA flash attention ----------------
__global__ __launch_bounds__(256) void k_attn_mfma(const unsigned short* __restrict__ qkv,
                                                   const int* __restrict__ mask,
                                                   unsigned short* __restrict__ ctx){
  int qt = blockIdx.x, h = blockIdx.y, b = blockIdx.z;
  int tid = threadIdx.x;
  int lane = tid & 63, w = tid >> 6;
  int lr = lane & 15, lg = lane >> 4;

  __shared__ __attribute__((aligned(16))) unsigned short Ks[64][72];
  __shared__ __attribute__((aligned(16))) unsigned short VsT[64][72];
  __shared__ __attribute__((aligned(16))) unsigned short Ps[4][16][72];
  __shared__ float biasS[64];

  int qrow = b * 512 + qt * 64 + w * 16 + lr;
  const unsigned short* qp = qkv + (size_t)qrow * 2304 + h * 64 + lg * 8;
  bf16x8 qa[2];
  qa[0] = *(const bf16x8*)(qp);
  qa[1] = *(const bf16x8*)(qp + 32);

  f32x4 oacc[4];
  #pragma unroll
  for (int dt = 0; dt < 4; dt++) oacc[dt] = (f32x4){0.f, 0.f, 0.f, 0.f};
  float mrow[4], lrow[4];
  #pragma unroll
  for (int j = 0; j < 4; j++){ mrow[j] = -1e30f; lrow[j] = 0.f; }

  for (int c = 0; c < 8; c++){
    __syncthreads();
    {
      int r = tid >> 2, d0 = (tid & 3) << 4;
      const unsigned short* kp = qkv + (size_t)(b * 512 + c * 64 + r) * 2304 + 768 + h * 64 + d0;
      u16x8 k0 = *(const u16x8*)kp;
      u16x8 k1 = *(const u16x8*)(kp + 8);
      *(u16x8*)(&Ks[r][d0]) = k0;
      *(u16x8*)(&Ks[r][d0 + 8]) = k1;
    }
    {
      int kv = tid & 63, d0 = (tid >> 6) << 4;
      const unsigned short* vp = qkv + (size_t)(b * 512 + c * 64 + kv) * 2304 + 1536 + h * 64 + d0;
      u16x8 v0 = *(const u16x8*)vp;
      u16x8 v1 = *(const u16x8*)(vp + 8);
      #pragma unroll
      for (int j2 = 0; j2 < 8; j2++){
        VsT[d0 + j2][kv] = (unsigned short)v0[j2];
        VsT[d0 + 8 + j2][kv] = (unsigned short)v1[j2];
      }
    }
    if (tid < 64) biasS[tid] = (1.f - (float)mask[b * 512 + c * 64 + tid]) * -1e9f;
    __syncthreads();

    f32x4 sacc[4];
    #pragma unroll
    for (int n = 0; n < 4; n++) sacc[n] = (f32x4){0.f, 0.f, 0.f, 0.f};
    #pragma unroll
    for (int kk = 0; kk < 2; kk++){
      bf16x8 kb[4];
      #pragma unroll
      for (int n = 0; n < 4; n++)
        kb[n] = *(const bf16x8*)(&Ks[lr + 16 * n][lg * 8 + 32 * kk]);
      #pragma unroll
      for (int n = 0; n < 4; n++)
        sacc[n] = __builtin_amdgcn_mfma_f32_16x16x32_bf16(qa[kk], kb[n], sacc[n], 0, 0, 0);
    }

    float pv[4][4];
    #pragma unroll
    for (int n = 0; n < 4; n++){
      float bsv = biasS[lr + 16 * n];
      #pragma unroll
      for (int j = 0; j < 4; j++) pv[n][j] = sacc[n][j] * 0.125f + bsv;
    }
    #pragma unroll
    for (int j = 0; j < 4; j++){
      float mx = fmaxf(fmaxf(pv[0][j], pv[1][j]), fmaxf(pv[2][j], pv[3][j]));
      mx = fmaxf(mx, __shfl_xor(mx, 1));
      mx = fmaxf(mx, __shfl_xor(mx, 2));
      mx = fmaxf(mx, __shfl_xor(mx, 4));
      mx = fmaxf(mx, __shfl_xor(mx, 8));
      float mnew = fmaxf(mrow[j], mx);
      float corr = __expf(mrow[j] - mnew);
      float ps = 0.f;
      #pragma unroll
      for (int n = 0; n < 4; n++){
        pv[n][j] = __expf(pv[n][j] - mnew);
        ps += pv[n][j];
      }
      ps += __shfl_xor(ps, 1);
      ps += __shfl_xor(ps, 2);
      ps += __shfl_xor(ps, 4);
      ps += __shfl_xor(ps, 8);
      lrow[j] = lrow[j] * corr + ps;
      mrow[j] = mnew;
      #pragma unroll
      for (int dt = 0; dt < 4; dt++) oacc[dt][j] *= corr;
    }

    #pragma unroll
    for (int n = 0; n < 4; n++)
      #pragma unroll
      for (int j = 0; j < 4; j++)
        Ps[w][4 * lg + j][lr + 16 * n] = f2bf(pv[n][j]);

    #pragma unroll
    for (int kk = 0; kk < 2; kk++){
      bf16x8 pa = *(const bf16x8*)(&Ps[w][lr][lg * 8 + 32 * kk]);
      bf16x8 vb[4];
      #pragma unroll
      for (int dt = 0; dt < 4; dt++)
        vb[dt] = *(const bf16x8*)(&VsT[lr + 16 * dt][lg * 8 + 32 * kk]);
      #pragma unroll
      for (int dt = 0; dt < 4; dt++)
        oacc[dt] = __builtin_amdgcn_mfma_f32_16x16x32_bf16(pa, vb[dt], oacc[dt], 0, 0, 0);
    }
  }

  #pragma unroll
  for (int j = 0; j < 4; j++){
    float inv = 1.f / lrow[j];
    int row = b * 512 + qt * 64 + w * 16 + 4 * lg + j;
    unsigned short* o = ctx + (size_t)row * 768 + h * 64;
    #pragma unroll
    for (int dt = 0; dt < 4; dt++)
      o[lr + 16 * dt] = f2bf(oacc[dt][j] * inv);
  }
}

// ---------------- span heads ----------------
__global__ __launch_bounds__(256) void k_heads(const unsigned short* __restrict__ x,
                        const float* __restrict__ sw, const float* __restrict__ sb,
                        const float* __restrict__ ew, const float* __restrict__ eb,
                        const float* __restrict__ mw,
                        float* __restrict__ out, float* __restrict__ sproj, float* __restrict__ eproj){
  int row = blockIdx.x;
  int t = threadIdx.x;
  float a0 = 0.f, a1 = 0.f, a2 = 0.f, a3 = 0.f;
  #pragma unroll
  for (int i = 0; i < 3; i++){
    int c = t + i * 256;
    float v = bf2f(x[(size_t)row * 768 + c]);
    a0 += v * sw[c]; a1 += v * ew[c]; a2 += v * mw[c]; a3 += v * mw[768 + c];
  }
  #pragma unroll
  for (int o = 32; o > 0; o >>= 1){
    a0 += __shfl_down(a0, o); a1 += __shfl_down(a1, o);
    a2 += __shfl_down(a2, o); a3 += __shfl_down(a3, o);
  }
  __shared__ float red[4][4];
  int wv = t >> 6;
  if ((t & 63) == 0){ red[0][wv] = a0; red[1][wv] = a1; red[2][wv] = a2; red[3][wv] = a3; }
  __syncthreads();
  if (t == 0){
    float s0 = red[0][0] + red[0][1] + red[0][2] + red[0][3];
    float s1 = red[1][0] + red[1][1] + red[1][2] + red[1][3];
    float s2 = red[2][0] + red[2][1] + red[2][2] + red[2][3];
    float s3 = red[3][0] + red[3][1] + red[3][2] + red[3][3];
    out[row] = s0 + sb[0];
    out[4096 + row] = s1 + eb[0];
    sproj[row] = s2;
    eproj[row] = s3;
  }
}

__global__ __launch_bounds__(256) void k_match(const float* __restrict__ sproj, const float* __restrict__ eproj,
                        const float* __restrict__ mb, float* __restrict__ out){
  int idx = blockIdx.x * 256 + threadIdx.x;
  int j4 = idx & 127;
  int rest = idx >> 7;
  float sp = sproj[rest] + mb[0];
  const float* ep = eproj + ((rest >> 9) << 9) + j4 * 4;
  float4 r;
  r.x = sp + ep[0]; r.y = sp + ep[1]; r.z = sp + ep[2]; r.w = sp + ep[3];
  ((float4*)(out + 8192))[idx] = r;
}

extern "C" void kernel_launch(void* const* d_in, const int* in_sizes, int n_in,
                              void* d_out, int out_size, void* d_ws, size_t ws_size,
                              hipStream_t stream){
  (void)in_sizes; (void)n_in; (void)out_size; (void)ws_size;
  const int*   ids  = (const int*)d_in[0];
  const int*   tts  = (const int*)d_in[1];
  const int*   mask = (const int*)d_in[2];
  const float* we   = (const float*)d_in[3];
  const float* pe   = (const float*)d_in[4];
  const float* te   = (const float*)d_in[5];
  const float* eg   = (const float*)d_in[6];
  const float* ebv  = (const float*)d_in[7];
  const float* Wq   = (const float*)d_in[8];
  const float* bq   = (const float*)d_in[9];
  const float* Wk   = (const float*)d_in[10];
  const float* bk   = (const float*)d_in[11];
  const float* Wv   = (const float*)d_in[12];
  const float* bv   = (const float*)d_in[13];
  const float* Wo   = (const float*)d_in[14];
  const float* bo   = (const float*)d_in[15];
  const float* ag   = (const float*)d_in[16];
  const float* ab   = (const float*)d_in[17];
  const float* W1   = (const float*)d_in[18];
  const float* b1   = (const float*)d_in[19];
  const float* W2   = (const float*)d_in[20];
  const float* b2   = (const float*)d_in[21];
  const float* fg   = (const float*)d_in[22];
  const float* fb   = (const float*)d_in[23];
  const float* sw   = (const float*)d_in[24];
  const float* sb   = (const float*)d_in[25];
  const float* ew   = (const float*)d_in[26];
  const float* ebd  = (const float*)d_in[27];
  const float* mw   = (const float*)d_in[28];
  const float* mb   = (const float*)d_in[29];
  float* out = (float*)d_out;

  // workspace layout (bytes)
  char* ws = (char*)d_ws;
  unsigned short* Y = (unsigned short*)(ws + 12582912);       // bf16
  float* SPROJ  = (float*)(ws + 25165824);
  float* EPROJ  = (float*)(ws + 25182208);
  float* BQKV   = (float*)(ws + 25198592);
  unsigned short* XB    = (unsigned short*)(ws + 25235456);   // residual stream, bf16
  unsigned short* QKV   = (unsigned short*)(ws + 31526912);   // 18874368
  unsigned short* CTX   = (unsigned short*)(ws + 50401280);
  unsigned short* HBUF  = (unsigned short*)(ws + 56692736);   // 25165824
  unsigned short* WTALL = (unsigned short*)(ws + 81858560);
  unsigned short* Y2    = (unsigned short*)(ws + 31526912);   // Wo/FF2 partials over dead QKV

  k_prep_weights<<<6912, 256, 0, stream>>>(Wq, Wk, Wv, Wo, W1, W2, WTALL);
  k_prep_bias<<<36, 256, 0, stream>>>(bq, bk, bv, BQKV);
  k_embed_ln<<<4096, 256, 0, stream>>>(ids, tts, we, pe, te, eg, ebv, XB);

  for (int l = 0; l < NL_; l++){
    unsigned short* wt = WTALL + (size_t)l * 7077888;
    // QKV: M=4096 N=2304 K=768 -> 8-phase 256^2, 144 blocks
    k_gemm8<0><<<dim3(9, 16), 512, 0, stream>>>(XB, wt, BQKV + l * 2304, QKV, 4096, 2304, 768);
    k_attn_mfma<<<dim3(8, 12, 8), 256, 0, stream>>>(QKV, mask, CTX);
    // Wo: N=768 K=768, 128^2 split-K x4 -> 768 blocks
    k_gemm<0><<<dim3(6, 32, 4), 256, 0, stream>>>(CTX, wt + 1769472, bo + l * 768, Y, Y2, 4096, 768, 768, 192);
    k_add_ln<3><<<4096, 128, 0, stream>>>(XB, Y, Y2, ag + l * 768, ab + l * 768);
    // FF1: N=3072 K=768 -> 8-phase 256^2 with fused gelu, 192 blocks
    k_gemm8<1><<<dim3(12, 16), 512, 0, stream>>>(XB, wt + 2359296, b1 + l * 3072, HBUF, 4096, 3072, 768);
    // FF2: N=768 K=3072, 128^2 split-K x4 -> 768 blocks
    k_gemm<0><<<dim3(6, 32, 4), 256, 0, stream>>>(HBUF, wt + 4718592, b2 + l * 768, Y, Y2, 4096, 768, 3072, 768);
    k_add_ln<3><<<4096, 128, 0, stream>>>(XB, Y, Y2, fg + l * 768, fb + l * 768);
  }

  k_heads<<<4096, 256, 0, stream>>>(XB, sw, sb, ew, ebd, mw, out, SPROJ, EPROJ);
  k_match<<<2048, 256, 0, stream>>>(SPROJ, EPROJ, mb, out);
}

// Round 13
// 666.767 us; speedup vs baseline: 1.1334x; 1.1334x over previous
//
#include <hip/hip_runtime.h>

#define B_   8
#define L_   512
#define H_   768
#define NH_  12
#define DFF_ 3072
#define NL_  4
#define HD_  64
#define M_   4096

typedef __bf16 bf16x8 __attribute__((ext_vector_type(8)));
typedef float f32x4 __attribute__((ext_vector_type(4)));
typedef unsigned short u16x8 __attribute__((ext_vector_type(8)));

__device__ inline float bf2f(unsigned short u){
  union { unsigned int i; float f; } v; v.i = ((unsigned int)u) << 16; return v.f;
}
__device__ inline unsigned short f2bf(float f){
  union { float f; unsigned int i; } v; v.f = f;
  unsigned int x = v.i;
  return (unsigned short)((x + 0x7fffu + ((x >> 16) & 1u)) >> 16);
}

// ---------------- weight prep v3: transpose fp32 [R][C] -> bf16 [C][R] ----------------
// 128 src-rows x 64 src-cols per block: dst writes are 256B contiguous (16 thr x 16B),
// reads 256B-coalesced float4. LDS float[128][65] (odd dword stride: phase-1 writes
// conflict-free, phase-2 reads <=4-way). 864 tiles/layer x 4 layers = 3456 blocks.
__global__ __launch_bounds__(256) void k_prep_weights(const float* __restrict__ Wq, const float* __restrict__ Wk,
                               const float* __restrict__ Wv, const float* __restrict__ Wo,
                               const float* __restrict__ W1, const float* __restrict__ W2,
                               unsigned short* __restrict__ wTall){
  __shared__ float tile[128][65];   // 33.3 KB
  int id = blockIdx.x;
  int layer = id / 864;
  int r = id % 864;
  unsigned short* wt = wTall + (size_t)layer * 7077888;
  const float* src; unsigned short* dst; int R, C, tr, tilesC;
  if (r < 288){
    int mat = r / 72; tr = r % 72; R = 768; C = 768; tilesC = 12;
    const float* s;
    if (mat == 0) s = Wq; else if (mat == 1) s = Wk; else if (mat == 2) s = Wv; else s = Wo;
    src = s + (size_t)layer * 589824;
    dst = wt + (size_t)mat * 589824;
  } else if (r < 576){
    tr = r - 288; R = 768; C = 3072; tilesC = 48;
    src = W1 + (size_t)layer * 2359296; dst = wt + 2359296;
  } else {
    tr = r - 576; R = 3072; C = 768; tilesC = 12;
    src = W2 + (size_t)layer * 2359296; dst = wt + 4718592;
  }
  int rows0 = (tr / tilesC) << 7;   // 128-row src tile
  int c0 = (tr % tilesC) << 6;      // 64-col src tile
  int tid = threadIdx.x;

  // phase 1: coalesced float4 reads -> LDS (row-major)
  #pragma unroll
  for (int i = 0; i < 8; i++){
    int flat4 = i * 256 + tid;          // 0..2047
    int row = flat4 >> 4;               // 0..127
    int c4 = (flat4 & 15) << 2;         // 0..60
    float4 v = *(const float4*)(src + (size_t)(rows0 + row) * C + c0 + c4);
    tile[row][c4] = v.x; tile[row][c4 + 1] = v.y;
    tile[row][c4 + 2] = v.z; tile[row][c4 + 3] = v.w;
  }
  __syncthreads();

  // phase 2: transposed u16x8 gather -> 256B-contiguous dst writes
  #pragma unroll
  for (int i2 = 0; i2 < 4; i2++){
    int flatc = i2 * 256 + tid;         // 0..1023
    int dcol = flatc >> 4;              // src col = dst row, 0..63
    int ch = flatc & 15;                // 8-row chunk, 0..15
    u16x8 o;
    #pragma unroll
    for (int j = 0; j < 8; j++) o[j] = f2bf(tile[ch * 8 + j][dcol]);
    *(u16x8*)(dst + (size_t)(c0 + dcol) * R + rows0 + ch * 8) = o;
  }
}

__global__ void k_prep_bias(const float* __restrict__ bq, const float* __restrict__ bk,
                            const float* __restrict__ bv, float* __restrict__ out){
  int i = blockIdx.x * 256 + threadIdx.x;
  int layer = i / 2304, c = i % 2304;
  float v;
  if (c < 768) v = bq[layer * 768 + c];
  else if (c < 1536) v = bk[layer * 768 + c - 768];
  else v = bv[layer * 768 + c - 1536];
  out[i] = v;
}

// ---------------- embedding + LN ----------------
__global__ __launch_bounds__(256) void k_embed_ln(const int* __restrict__ ids, const int* __restrict__ tts,
                           const float* __restrict__ we, const float* __restrict__ pe,
                           const float* __restrict__ te, const float* __restrict__ g,
                           const float* __restrict__ b,
                           unsigned short* __restrict__ xb){
  int row = blockIdx.x;
  int l = row & 511;
  int id = ids[row], tt = tts[row];
  int t = threadIdx.x;
  float v[3]; float s = 0.f, s2 = 0.f;
  #pragma unroll
  for (int i = 0; i < 3; i++){
    int c = t + i * 256;
    float val = we[(size_t)id * 768 + c] + pe[(size_t)l * 768 + c] + te[(size_t)tt * 768 + c];
    v[i] = val; s += val; s2 += val * val;
  }
  #pragma unroll
  for (int o = 32; o > 0; o >>= 1){ s += __shfl_down(s, o); s2 += __shfl_down(s2, o); }
  __shared__ float red[2][4];
  int wv = t >> 6;
  if ((t & 63) == 0){ red[0][wv] = s; red[1][wv] = s2; }
  __syncthreads();
  s = red[0][0] + red[0][1] + red[0][2] + red[0][3];
  s2 = red[1][0] + red[1][1] + red[1][2] + red[1][3];
  float mean = s * (1.f / 768.f);
  float var = s2 * (1.f / 768.f) - mean * mean;
  float rstd = rsqrtf(var + 1e-12f);
  #pragma unroll
  for (int i = 0; i < 3; i++){
    int c = t + i * 256;
    float nv = (v[i] - mean) * rstd * g[c] + b[c];
    xb[(size_t)row * 768 + c] = f2bf(nv);
  }
}

// ---------------- residual add + N2 bf16 partials + LN (vectorized) ----------------
template<int N2>
__global__ __launch_bounds__(128) void k_add_ln(unsigned short* __restrict__ xb,
                         const unsigned short* __restrict__ y,
                         const unsigned short* __restrict__ y2,
                         const float* __restrict__ g, const float* __restrict__ b){
  int row = blockIdx.x;
  int t = threadIdx.x;
  float v[8];
  float s = 0.f, s2 = 0.f;
  size_t base = (size_t)row * 768 + t * 8;
  if (t < 96){
    u16x8 a = *(const u16x8*)(xb + base);
    u16x8 yy = *(const u16x8*)(y + base);
    #pragma unroll
    for (int j = 0; j < 8; j++) v[j] = bf2f(a[j]) + bf2f(yy[j]);
    #pragma unroll
    for (int q = 0; q < N2; q++){
      u16x8 p = *(const u16x8*)(y2 + (size_t)q * 4096 * 768 + base);
      #pragma unroll
      for (int j = 0; j < 8; j++) v[j] += bf2f(p[j]);
    }
    #pragma unroll
    for (int j = 0; j < 8; j++){ s += v[j]; s2 += v[j] * v[j]; }
  }
  #pragma unroll
  for (int o = 32; o > 0; o >>= 1){ s += __shfl_down(s, o); s2 += __shfl_down(s2, o); }
  __shared__ float red[2][2];
  int wv = t >> 6;
  if ((t & 63) == 0){ red[0][wv] = s; red[1][wv] = s2; }
  __syncthreads();
  s = red[0][0] + red[0][1];
  s2 = red[1][0] + red[1][1];
  float mean = s * (1.f / 768.f);
  float var = s2 * (1.f / 768.f) - mean * mean;
  float rstd = rsqrtf(var + 1e-12f);
  if (t < 96){
    f32x4 g0 = *(const f32x4*)(g + t * 8);
    f32x4 g1 = *(const f32x4*)(g + t * 8 + 4);
    f32x4 b0 = *(const f32x4*)(b + t * 8);
    f32x4 b1 = *(const f32x4*)(b + t * 8 + 4);
    u16x8 o8;
    #pragma unroll
    for (int j = 0; j < 4; j++) o8[j] = f2bf((v[j] - mean) * rstd * g0[j] + b0[j]);
    #pragma unroll
    for (int j = 0; j < 4; j++) o8[4 + j] = f2bf((v[4 + j] - mean) * rstd * g1[j] + b1[j]);
    *(u16x8*)(xb + base) = o8;
  }
}

// ---------------- bf16 MFMA GEMM, m97 structure (single 32KB buffer) + T2 swizzle ----------------
// Proven best (R5/R8/R10): 3-4 blocks/CU cross-block overlap is the lever; 256^2 and
// deep pipelines both refuted at these shapes (R6/R12: ~110us regardless of schedule).
template<int ACT>
__global__ __launch_bounds__(256, 4) void k_gemm(const unsigned short* __restrict__ A,
                                              const unsigned short* __restrict__ BT,
                                              const float* __restrict__ bias,
                                              unsigned short* __restrict__ Cout,
                                              unsigned short* __restrict__ Cout2,
                                              int M, int N, int K, int Ksub){
  __shared__ __attribute__((aligned(16))) unsigned short smem[16384]; // As | Bs, 32 KB
  unsigned short* As = smem;
  unsigned short* Bs = smem + 8192;
  int tid = threadIdx.x;
  int lane = tid & 63, wave = tid >> 6;
  int lr = lane & 15, lg = lane >> 4;

  int gx = gridDim.x;
  int nwg = gx * gridDim.y;
  int flat = blockIdx.y * gx + blockIdx.x;
  int cpx = nwg >> 3;
  int swz = (flat & 7) * cpx + (flat >> 3);
  int bx = swz % gx, by = swz / gx;

  int bm0 = by * 128, bn0 = bx * 128;
  int wr = wave >> 1, wc = wave & 1;
  int kz = blockIdx.z * Ksub;

  f32x4 acc[4][4];
  #pragma unroll
  for (int m = 0; m < 4; m++)
    #pragma unroll
    for (int n = 0; n < 4; n++)
      acc[m][n] = (f32x4){0.f, 0.f, 0.f, 0.f};

  int scol = (((lane & 7) ^ (lane >> 3)) << 3);
  const unsigned short* gaBase = A + (size_t)(bm0 + (lane >> 3)) * K + kz + scol;
  const unsigned short* gbBase = BT + (size_t)(bn0 + (lane >> 3)) * K + kz + scol;

  int nk = Ksub >> 6;
  for (int t = 0; t < nk; t++){
    if (t) __syncthreads();
    const unsigned short* gA = gaBase + (t << 6);
    const unsigned short* gB = gbBase + (t << 6);
    #pragma unroll
    for (int i = 0; i < 4; i++){
      size_t ro = (size_t)((wave * 4 + i) * 8) * K;
      __builtin_amdgcn_global_load_lds(
        (const __attribute__((address_space(1))) void*)(gA + ro),
        (__attribute__((address_space(3))) void*)(As + (wave * 4 + i) * 512), 16, 0, 0);
      __builtin_amdgcn_global_load_lds(
        (const __attribute__((address_space(1))) void*)(gB + ro),
        (__attribute__((address_space(3))) void*)(Bs + (wave * 4 + i) * 512), 16, 0, 0);
    }
    __syncthreads();
    #pragma unroll
    for (int kk = 0; kk < 2; kk++){
      bf16x8 av[4], bv[4];
      #pragma unroll
      for (int m = 0; m < 4; m++)
        av[m] = *(const bf16x8*)(As + (wr * 64 + m * 16 + lr) * 64 + (((4 * kk + lg) ^ (lr & 7)) << 3));
      #pragma unroll
      for (int n = 0; n < 4; n++)
        bv[n] = *(const bf16x8*)(Bs + (wc * 64 + n * 16 + lr) * 64 + (((4 * kk + lg) ^ (lr & 7)) << 3));
      #pragma unroll
      for (int m = 0; m < 4; m++)
        #pragma unroll
        for (int n = 0; n < 4; n++)
          acc[m][n] = __builtin_amdgcn_mfma_f32_16x16x32_bf16(av[m], bv[n], acc[m][n], 0, 0, 0);
    }
  }
  __syncthreads();

  int r0 = wr * 64 + 4 * lg;
  int c0 = wc * 64 + lr;
  unsigned short* cs = smem;
  bool z0 = (blockIdx.z == 0);
  #pragma unroll
  for (int n = 0; n < 4; n++){
    int c = c0 + 16 * n;
    float bsv = z0 ? bias[bn0 + c] : 0.f;
    #pragma unroll
    for (int m = 0; m < 4; m++)
      #pragma unroll
      for (int j = 0; j < 4; j++){
        float v = acc[m][n][j] + bsv;
        if (ACT == 1) v = 0.5f * v * (1.f + erff(v * 0.70710678118f));
        cs[(r0 + m * 16 + j) * 128 + c] = f2bf(v);
      }
  }
  __syncthreads();
  unsigned short* Cb = z0 ? Cout : (Cout2 + (size_t)(blockIdx.z - 1) * M * N);
  #pragma unroll
  for (int p = 0; p < 8; p++){
    int idx = p * 2048 + tid * 8;
    int row = idx >> 7, col = idx & 127;
    u16x8 v = *(const u16x8*)(cs + idx);
    *(u16x8*)(Cb + (size_t)(bm0 + row) * N + bn0 + col) = v;
  }
}

// ---------------- fused FF1 reduce: h = gelu(h + p1) (bf16, x8 vectorized) ----------------
__global__ __launch_bounds__(256) void k_gelu_reduce(unsigned short* __restrict__ h,
                                                     const unsigned short* __restrict__ p1){
  size_t i = ((size_t)blockIdx.x * 256 + threadIdx.x) * 8;
  u16x8 a = *(const u16x8*)(h + i);
  u16x8 b = *(const u16x8*)(p1 + i);
  u16x8 o;
  #pragma unroll
  for (int j = 0; j < 8; j++){
    float v = bf2f(a[j]) + bf2f(b[j]);
    v = 0.5f * v * (1.f + erff(v * 0.70710678118f));
    o[j] = f2bf(v);
  }
  *(u16x8*)(h + i) = o;
}

// ---------------- MFMA flash attention (single QKV input — L2-resident) ----------------
__global__ __launch_bounds__(256) void k_attn_mfma(const unsigned short* __restrict__ qkv,
                                                   const int* __restrict__ mask,
                                                   unsigned short* __restrict__ ctx){
  int qt = blockIdx.x, h = blockIdx.y, b = blockIdx.z;
  int tid = threadIdx.x;
  int lane = tid & 63, w = tid >> 6;
  int lr = lane & 15, lg = lane >> 4;

  __shared__ __attribute__((aligned(16))) unsigned short Ks[64][72];
  __shared__ __attribute__((aligned(16))) unsigned short VsT[64][72];
  __shared__ __attribute__((aligned(16))) unsigned short Ps[4][16][72];
  __shared__ float biasS[64];

  int qrow = b * 512 + qt * 64 + w * 16 + lr;
  const unsigned short* qp = qkv + (size_t)qrow * 2304 + h * 64 + lg * 8;
  bf16x8 qa[2];
  qa[0] = *(const bf16x8*)(qp);
  qa[1] = *(const bf16x8*)(qp + 32);

  f32x4 oacc[4];
  #pragma unroll
  for (int dt = 0; dt < 4; dt++) oacc[dt] = (f32x4){0.f, 0.f, 0.f, 0.f};
  float mrow[4], lrow[4];
  #pragma unroll
  for (int j = 0; j < 4; j++){ mrow[j] = -1e30f; lrow[j] = 0.f; }

  for (int c = 0; c < 8; c++){
    __syncthreads();
    {
      int r = tid >> 2, d0 = (tid & 3) << 4;
      const unsigned short* kp = qkv + (size_t)(b * 512 + c * 64 + r) * 2304 + 768 + h * 64 + d0;
      u16x8 k0 = *(const u16x8*)kp;
      u16x8 k1 = *(const u16x8*)(kp + 8);
      *(u16x8*)(&Ks[r][d0]) = k0;
      *(u16x8*)(&Ks[r][d0 + 8]) = k1;
    }
    {
      int kv = tid & 63, d0 = (tid >> 6) << 4;
      const unsigned short* vp = qkv + (size_t)(b * 512 + c * 64 + kv) * 2304 + 1536 + h * 64 + d0;
      u16x8 v0 = *(const u16x8*)vp;
      u16x8 v1 = *(const u16x8*)(vp + 8);
      #pragma unroll
      for (int j2 = 0; j2 < 8; j2++){
        VsT[d0 + j2][kv] = (unsigned short)v0[j2];
        VsT[d0 + 8 + j2][kv] = (unsigned short)v1[j2];
      }
    }
    if (tid < 64) biasS[tid] = (1.f - (float)mask[b * 512 + c * 64 + tid]) * -1e9f;
    __syncthreads();

    f32x4 sacc[4];
    #pragma unroll
    for (int n = 0; n < 4; n++) sacc[n] = (f32x4){0.f, 0.f, 0.f, 0.f};
    #pragma unroll
    for (int kk = 0; kk < 2; kk++){
      bf16x8 kb[4];
      #pragma unroll
      for (int n = 0; n < 4; n++)
        kb[n] = *(const bf16x8*)(&Ks[lr + 16 * n][lg * 8 + 32 * kk]);
      #pragma unroll
      for (int n = 0; n < 4; n++)
        sacc[n] = __builtin_amdgcn_mfma_f32_16x16x32_bf16(qa[kk], kb[n], sacc[n], 0, 0, 0);
    }

    float pv[4][4];
    #pragma unroll
    for (int n = 0; n < 4; n++){
      float bsv = biasS[lr + 16 * n];
      #pragma unroll
      for (int j = 0; j < 4; j++) pv[n][j] = sacc[n][j] * 0.125f + bsv;
    }
    #pragma unroll
    for (int j = 0; j < 4; j++){
      float mx = fmaxf(fmaxf(pv[0][j], pv[1][j]), fmaxf(pv[2][j], pv[3][j]));
      mx = fmaxf(mx, __shfl_xor(mx, 1));
      mx = fmaxf(mx, __shfl_xor(mx, 2));
      mx = fmaxf(mx, __shfl_xor(mx, 4));
      mx = fmaxf(mx, __shfl_xor(mx, 8));
      float mnew = fmaxf(mrow[j], mx);
      float corr = __expf(mrow[j] - mnew);
      float ps = 0.f;
      #pragma unroll
      for (int n = 0; n < 4; n++){
        pv[n][j] = __expf(pv[n][j] - mnew);
        ps += pv[n][j];
      }
      ps += __shfl_xor(ps, 1);
      ps += __shfl_xor(ps, 2);
      ps += __shfl_xor(ps, 4);
      ps += __shfl_xor(ps, 8);
      lrow[j] = lrow[j] * corr + ps;
      mrow[j] = mnew;
      #pragma unroll
      for (int dt = 0; dt < 4; dt++) oacc[dt][j] *= corr;
    }

    #pragma unroll
    for (int n = 0; n < 4; n++)
      #pragma unroll
      for (int j = 0; j < 4; j++)
        Ps[w][4 * lg + j][lr + 16 * n] = f2bf(pv[n][j]);

    #pragma unroll
    for (int kk = 0; kk < 2; kk++){
      bf16x8 pa = *(const bf16x8*)(&Ps[w][lr][lg * 8 + 32 * kk]);
      bf16x8 vb[4];
      #pragma unroll
      for (int dt = 0; dt < 4; dt++)
        vb[dt] = *(const bf16x8*)(&VsT[lr + 16 * dt][lg * 8 + 32 * kk]);
      #pragma unroll
      for (int dt = 0; dt < 4; dt++)
        oacc[dt] = __builtin_amdgcn_mfma_f32_16x16x32_bf16(pa, vb[dt], oacc[dt], 0, 0, 0);
    }
  }

  #pragma unroll
  for (int j = 0; j < 4; j++){
    float inv = 1.f / lrow[j];
    int row = b * 512 + qt * 64 + w * 16 + 4 * lg + j;
    unsigned short* o = ctx + (size_t)row * 768 + h * 64;
    #pragma unroll
    for (int dt = 0; dt < 4; dt++)
      o[lr + 16 * dt] = f2bf(oacc[dt][j] * inv);
  }
}

// ---------------- span heads (bf16 input) ----------------
__global__ __launch_bounds__(256) void k_heads(const unsigned short* __restrict__ x,
                        const float* __restrict__ sw, const float* __restrict__ sb,
                        const float* __restrict__ ew, const float* __restrict__ eb,
                        const float* __restrict__ mw,
                        float* __restrict__ out, float* __restrict__ sproj, float* __restrict__ eproj){
  int row = blockIdx.x;
  int t = threadIdx.x;
  float a0 = 0.f, a1 = 0.f, a2 = 0.f, a3 = 0.f;
  #pragma unroll
  for (int i = 0; i < 3; i++){
    int c = t + i * 256;
    float v = bf2f(x[(size_t)row * 768 + c]);
    a0 += v * sw[c]; a1 += v * ew[c]; a2 += v * mw[c]; a3 += v * mw[768 + c];
  }
  #pragma unroll
  for (int o = 32; o > 0; o >>= 1){
    a0 += __shfl_down(a0, o); a1 += __shfl_down(a1, o);
    a2 += __shfl_down(a2, o); a3 += __shfl_down(a3, o);
  }
  __shared__ float red[4][4];
  int wv = t >> 6;
  if ((t & 63) == 0){ red[0][wv] = a0; red[1][wv] = a1; red[2][wv] = a2; red[3][wv] = a3; }
  __syncthreads();
  if (t == 0){
    float s0 = red[0][0] + red[0][1] + red[0][2] + red[0][3];
    float s1 = red[1][0] + red[1][1] + red[1][2] + red[1][3];
    float s2 = red[2][0] + red[2][1] + red[2][2] + red[2][3];
    float s3 = red[3][0] + red[3][1] + red[3][2] + red[3][3];
    out[row] = s0 + sb[0];
    out[4096 + row] = s1 + eb[0];
    sproj[row] = s2;
    eproj[row] = s3;
  }
}

__global__ __launch_bounds__(256) void k_match(const float* __restrict__ sproj, const float* __restrict__ eproj,
                        const float* __restrict__ mb, float* __restrict__ out){
  int idx = blockIdx.x * 256 + threadIdx.x;
  int j4 = idx & 127;
  int rest = idx >> 7;
  float sp = sproj[rest] + mb[0];
  const float* ep = eproj + ((rest >> 9) << 9) + j4 * 4;
  float4 r;
  r.x = sp + ep[0]; r.y = sp + ep[1]; r.z = sp + ep[2]; r.w = sp + ep[3];
  ((float4*)(out + 8192))[idx] = r;
}

extern "C" void kernel_launch(void* const* d_in, const int* in_sizes, int n_in,
                              void* d_out, int out_size, void* d_ws, size_t ws_size,
                              hipStream_t stream){
  (void)in_sizes; (void)n_in; (void)out_size; (void)ws_size;
  const int*   ids  = (const int*)d_in[0];
  const int*   tts  = (const int*)d_in[1];
  const int*   mask = (const int*)d_in[2];
  const float* we   = (const float*)d_in[3];
  const float* pe   = (const float*)d_in[4];
  const float* te   = (const float*)d_in[5];
  const float* eg   = (const float*)d_in[6];
  const float* ebv  = (const float*)d_in[7];
  const float* Wq   = (const float*)d_in[8];
  const float* bq   = (const float*)d_in[9];
  const float* Wk   = (const float*)d_in[10];
  const float* bk   = (const float*)d_in[11];
  const float* Wv   = (const float*)d_in[12];
  const float* bv   = (const float*)d_in[13];
  const float* Wo   = (const float*)d_in[14];
  const float* bo   = (const float*)d_in[15];
  const float* ag   = (const float*)d_in[16];
  const float* ab   = (const float*)d_in[17];
  const float* W1   = (const float*)d_in[18];
  const float* b1   = (const float*)d_in[19];
  const float* W2   = (const float*)d_in[20];
  const float* b2   = (const float*)d_in[21];
  const float* fg   = (const float*)d_in[22];
  const float* fb   = (const float*)d_in[23];
  const float* sw   = (const float*)d_in[24];
  const float* sb   = (const float*)d_in[25];
  const float* ew   = (const float*)d_in[26];
  const float* ebd  = (const float*)d_in[27];
  const float* mw   = (const float*)d_in[28];
  const float* mb   = (const float*)d_in[29];
  float* out = (float*)d_out;

  // workspace layout (bytes)
  char* ws = (char*)d_ws;
  unsigned short* P1 = (unsigned short*)(ws);                 // FF1 z=1 partial, 25165824 B
  unsigned short* Y = (unsigned short*)(ws + 12582912);       // 6291456 (bf16) — disjoint lifetime with P1
  float* SPROJ  = (float*)(ws + 25165824);
  float* EPROJ  = (float*)(ws + 25182208);
  float* BQKV   = (float*)(ws + 25198592);
  unsigned short* XB    = (unsigned short*)(ws + 25235456);   // residual stream, bf16
  unsigned short* QKV   = (unsigned short*)(ws + 31526912);   // 18874368
  unsigned short* CTX   = (unsigned short*)(ws + 50401280);
  unsigned short* HBUF  = (unsigned short*)(ws + 56692736);   // 25165824
  unsigned short* WTALL = (unsigned short*)(ws + 81858560);
  unsigned short* Y2    = (unsigned short*)(ws + 31526912);   // Wo/FF2 partials over dead QKV

  k_prep_weights<<<3456, 256, 0, stream>>>(Wq, Wk, Wv, Wo, W1, W2, WTALL);
  k_prep_bias<<<36, 256, 0, stream>>>(bq, bk, bv, BQKV);
  k_embed_ln<<<4096, 256, 0, stream>>>(ids, tts, we, pe, te, eg, ebv, XB);

  for (int l = 0; l < NL_; l++){
    unsigned short* wt = WTALL + (size_t)l * 7077888;
    // QKV: M=4096 N=2304 K=768 -> 576 blocks (z=1)
    k_gemm<0><<<dim3(18, 32, 1), 256, 0, stream>>>(XB, wt, BQKV + l * 2304, QKV, nullptr, 4096, 2304, 768, 768);
    k_attn_mfma<<<dim3(8, 12, 8), 256, 0, stream>>>(QKV, mask, CTX);
    // Wo: N=768 K=768, split-K x4 -> 768 blocks
    k_gemm<0><<<dim3(6, 32, 4), 256, 0, stream>>>(CTX, wt + 1769472, bo + l * 768, Y, Y2, 4096, 768, 768, 192);
    k_add_ln<3><<<4096, 128, 0, stream>>>(XB, Y, Y2, ag + l * 768, ab + l * 768);
    // FF1: N=3072 K=768, split-K x2 -> 1536 blocks; gelu in reduce
    k_gemm<0><<<dim3(24, 32, 2), 256, 0, stream>>>(XB, wt + 2359296, b1 + l * 3072, HBUF, P1, 4096, 3072, 768, 384);
    k_gelu_reduce<<<6144, 256, 0, stream>>>(HBUF, P1);
    // FF2: N=768 K=3072, split-K x4 -> 768 blocks
    k_gemm<0><<<dim3(6, 32, 4), 256, 0, stream>>>(HBUF, wt + 4718592, b2 + l * 768, Y, Y2, 4096, 768, 3072, 768);
    k_add_ln<3><<<4096, 128, 0, stream>>>(XB, Y, Y2, fg + l * 768, fb + l * 768);
  }

  k_heads<<<4096, 256, 0, stream>>>(XB, sw, sb, ew, ebd, mw, out, SPROJ, EPROJ);
  k_match<<<2048, 256, 0, stream>>>(SPROJ, EPROJ, mb, out);
}